// Round 13
// baseline (216.608 us; speedup 1.0000x reference)
//
#include <hip/hip_runtime.h>
#include <hip/hip_bf16.h>

#define E_DIM 128
#define L_DIM 64
#define HDIM 64

__device__ __forceinline__ float waveSum(float v) {
#pragma unroll
  for (int o = 32; o > 0; o >>= 1) v += __shfl_xor(v, o);
  return v;
}
__device__ __forceinline__ float waveMax(float v) {
#pragma unroll
  for (int o = 32; o > 0; o >>= 1) v = fmaxf(v, __shfl_xor(v, o));
  return v;
}
__device__ __forceinline__ float halfSum(float v) {  // reduce within 32 lanes
#pragma unroll
  for (int o = 16; o > 0; o >>= 1) v += __shfl_xor(v, o);
  return v;
}

__device__ __forceinline__ unsigned int f2bf(float f) {  // RNE
  unsigned int u = __float_as_uint(f);
  return (u + 0x7fffu + ((u >> 16) & 1u)) >> 16;
}
__device__ __forceinline__ float lo_bf(unsigned int q) {
  return __uint_as_float(q << 16);
}
__device__ __forceinline__ float hi_bf(unsigned int q) {
  return __uint_as_float(q & 0xffff0000u);
}

// Single merged convert pass for BOTH tables. Half-wave h handles global
// row 2*gw+h; user rows first, then item rows. Lane j covers dims
// 4j..4j+3; projection dots reduced over the 32-lane half.
__global__ __launch_bounds__(256) void convert_all(
    const float* __restrict__ user_src, const float* __restrict__ item_src,
    unsigned short* __restrict__ user_bf, unsigned short* __restrict__ item_bf,
    const float* __restrict__ w_uu, const float* __restrict__ w_uiu,
    const float* __restrict__ w_uui, float* __restrict__ pU0,
    float* __restrict__ pU1, float* __restrict__ pU2,
    float* __restrict__ pI1, float* __restrict__ pI2, int nUr, int nIr) {
  const int lane = threadIdx.x & 63;
  const int j = lane & 31;
  const int h = lane >> 5;
  const int gw = blockIdx.x * 4 + (threadIdx.x >> 6);
  const int r_all = gw * 2 + h;
  if (r_all >= nUr + nIr) return;

  const bool is_user = (r_all < nUr);
  const int r = is_user ? r_all : r_all - nUr;
  const float* src = is_user ? user_src : item_src;
  unsigned short* dst = is_user ? user_bf : item_bf;

  const float4 v = *(const float4*)(src + (long)r * E_DIM + j * 4);
  const unsigned int b0p = f2bf(v.x) | (f2bf(v.y) << 16);
  const unsigned int b1p = f2bf(v.z) | (f2bf(v.w) << 16);
  ((uint2*)dst)[(long)r * (E_DIM / 4) + j] = make_uint2(b0p, b1p);
  const float x0 = lo_bf(b0p), x1 = hi_bf(b0p);
  const float x2 = lo_bf(b1p), x3 = hi_bf(b1p);

  const float* wA = is_user ? w_uu : w_uiu;
  const float* wB = is_user ? w_uiu : w_uui;
  const float4 a4 = *(const float4*)(wA + E_DIM + j * 4);
  const float dA = halfSum(x0 * a4.x + x1 * a4.y + x2 * a4.z + x3 * a4.w);
  const float4 b4 = *(const float4*)(wB + E_DIM + j * 4);
  const float dB = halfSum(x0 * b4.x + x1 * b4.y + x2 * b4.z + x3 * b4.w);
  float dC = 0.f;
  if (is_user) {
    const float4 c4 = *(const float4*)(w_uui + E_DIM + j * 4);
    dC = halfSum(x0 * c4.x + x1 * c4.y + x2 * c4.z + x3 * c4.w);
  }
  if (j == 0) {
    if (is_user) {
      pU0[r] = dA;
      pU1[r] = dB;
      pU2[r] = dC;
    } else {
      pI1[r] = dA;
      pI2[r] = dB;
    }
  }
}

// One wave per (b, k). Logits from precomputed row projections (2 softmax
// butterflies total). Weighted sum: quarter-wave uint4 row loads (4 rows
// per wave instruction, R12) with DEPTH-2 rolling prefetch via explicit
// A/B scalar register sets. The it+=2 loop is pinned rolled with
// `#pragma unroll 1` so the compiler can't hoist all loads and repeat the
// R10 VGPR blowup (arrays+unroll -> VGPR 108 / occ 22%).
__global__ __launch_bounds__(256) void phase1_proj(
    const float* __restrict__ user_embs,  // fp32 (self rows)
    const unsigned short* __restrict__ user_bf,
    const unsigned short* __restrict__ item_bf,
    const float* __restrict__ projU0, const float* __restrict__ projU1,
    const float* __restrict__ projU2, const float* __restrict__ projI1,
    const float* __restrict__ projI2,
    const float* __restrict__ w_uu, const float* __restrict__ w_uiu,
    const float* __restrict__ w_uui, const float* __restrict__ W0,
    const float* __restrict__ b0, const float* __restrict__ w1,
    const int* __restrict__ uid, const int* __restrict__ nbr,
    const int* __restrict__ uiu, const int* __restrict__ uui,
    float* __restrict__ feats,     // [3][B][E]
    float* __restrict__ partials,  // [3][B]
    int B) {
  const int lane = threadIdx.x & 63;
  const int j = lane & 15;        // dim chunk: dims 8j..8j+7
  const int quarter = lane >> 4;  // 0..3: which row of a 4-row group
  const int wv = threadIdx.x >> 6;
  const int w_id = blockIdx.x * 4 + wv;
  const int b = w_id / 3;
  const int k = w_id - 3 * b;
  if (b >= B) return;  // grid exact for B%4==0

  __shared__ float sc[4][E_DIM];

  const int u = uid[b];
  const float2 self2 = *(const float2*)(user_embs + (long)u * E_DIM + lane * 2);

  const float* w = (k == 0) ? w_uu : (k == 1) ? w_uiu : w_uui;
  const float2 wa = *(const float2*)(w + lane * 2);
  const float2 wb = *(const float2*)(w + E_DIM + lane * 2);
  const float S1 = waveSum(self2.x * wa.x + self2.y * wa.y);
  const float S2 = waveSum(self2.x * wb.x + self2.y * wb.y);

  const bool is_uu = (k == 0);
  const float scale = is_uu ? 0.5f : (1.0f / 3.0f);
  // tables: k==0 -> user; k==1 (uiu) -> item,user; k==2 (uui) -> user,item
  const uint4* T0 = (const uint4*)((k == 1) ? item_bf : user_bf);
  const uint4* T1 = (const uint4*)((k == 1) ? user_bf : item_bf);
  const float* p0 = (k == 0) ? projU0 : (k == 1) ? projI1 : projU2;
  const float* p1 = (k == 1) ? projU1 : projI2;  // unused for k==0

  // lane l owns neighbor l's indices (coalesced)
  int i0_l, i1_l;
  if (is_uu) {
    i0_l = nbr[b * L_DIM + lane];
    i1_l = 0;
  } else {
    const int* mp = (k == 1) ? uiu : uui;
    i0_l = mp[(b * 2 + 0) * L_DIM + lane];
    i1_l = mp[(b * 2 + 1) * L_DIM + lane];
  }

  // ---- logits from projections (lane = neighbor, no per-l butterflies) --
  float d = p0[i0_l];
  if (!is_uu) d += p1[i1_l];
  float logit = S1 + scale * (S2 + d);
  logit = (logit > 0.f) ? logit : 0.01f * logit;  // leaky_relu
  if (i0_l == 0) logit += -100000000.0f;          // mask

  const float M = waveMax(logit);
  const float p = __expf(logit - M);
  const float Z = waveSum(p);
  const float a_l = p / Z;  // lane l: neighbor l's attention weight

  // ---- weighted sum: 4 rows/instruction, depth-2 A/B rolling prefetch --
  constexpr int RQ = E_DIM / 8;  // 16 uint4 per bf16 row
  float o0 = 0.f, o1 = 0.f, o2 = 0.f, o3 = 0.f;
  float o4 = 0.f, o5 = 0.f, o6 = 0.f, o7 = 0.f;

  // prologue: groups 0 (A) and 1 (B)
  int l4 = quarter;
  float aA = __shfl(a_l, l4);
  int i0 = __shfl(i0_l, l4);
  uint4 qA0 = T0[(long)i0 * RQ + j];
  uint4 qA1 = make_uint4(0, 0, 0, 0);
  if (!is_uu) {
    const int i1 = __shfl(i1_l, l4);
    qA1 = T1[(long)i1 * RQ + j];
  }
  l4 = 4 + quarter;
  float aB = __shfl(a_l, l4);
  i0 = __shfl(i0_l, l4);
  uint4 qB0 = T0[(long)i0 * RQ + j];
  uint4 qB1 = make_uint4(0, 0, 0, 0);
  if (!is_uu) {
    const int i1 = __shfl(i1_l, l4);
    qB1 = T1[(long)i1 * RQ + j];
  }

#pragma unroll 1
  for (int it = 0; it < L_DIM / 4; it += 2) {
    // ---- consume A (group it), refill A with group it+2 ----
    {
      const float a = aA;
      const uint4 qa = qA0;
      const uint4 qb = qA1;
      if (it + 2 < L_DIM / 4) {
        l4 = 4 * (it + 2) + quarter;
        aA = __shfl(a_l, l4);
        i0 = __shfl(i0_l, l4);
        qA0 = T0[(long)i0 * RQ + j];
        if (!is_uu) {
          const int i1 = __shfl(i1_l, l4);
          qA1 = T1[(long)i1 * RQ + j];
        }
      }
      float h0 = lo_bf(qa.x), h1 = hi_bf(qa.x);
      float h2 = lo_bf(qa.y), h3 = hi_bf(qa.y);
      float h4 = lo_bf(qa.z), h5 = hi_bf(qa.z);
      float h6 = lo_bf(qa.w), h7 = hi_bf(qa.w);
      if (!is_uu) {
        h0 += lo_bf(qb.x); h1 += hi_bf(qb.x);
        h2 += lo_bf(qb.y); h3 += hi_bf(qb.y);
        h4 += lo_bf(qb.z); h5 += hi_bf(qb.z);
        h6 += lo_bf(qb.w); h7 += hi_bf(qb.w);
      }
      o0 += a * h0; o1 += a * h1; o2 += a * h2; o3 += a * h3;
      o4 += a * h4; o5 += a * h5; o6 += a * h6; o7 += a * h7;
    }
    // ---- consume B (group it+1), refill B with group it+3 ----
    {
      const float a = aB;
      const uint4 qa = qB0;
      const uint4 qb = qB1;
      if (it + 3 < L_DIM / 4) {
        l4 = 4 * (it + 3) + quarter;
        aB = __shfl(a_l, l4);
        i0 = __shfl(i0_l, l4);
        qB0 = T0[(long)i0 * RQ + j];
        if (!is_uu) {
          const int i1 = __shfl(i1_l, l4);
          qB1 = T1[(long)i1 * RQ + j];
        }
      }
      float h0 = lo_bf(qa.x), h1 = hi_bf(qa.x);
      float h2 = lo_bf(qa.y), h3 = hi_bf(qa.y);
      float h4 = lo_bf(qa.z), h5 = hi_bf(qa.z);
      float h6 = lo_bf(qa.w), h7 = hi_bf(qa.w);
      if (!is_uu) {
        h0 += lo_bf(qb.x); h1 += hi_bf(qb.x);
        h2 += lo_bf(qb.y); h3 += hi_bf(qb.y);
        h4 += lo_bf(qb.z); h5 += hi_bf(qb.z);
        h6 += lo_bf(qb.w); h7 += hi_bf(qb.w);
      }
      o0 += a * h0; o1 += a * h1; o2 += a * h2; o3 += a * h3;
      o4 += a * h4; o5 += a * h5; o6 += a * h6; o7 += a * h7;
    }
  }
  // combine the 4 quarters (each summed 16 of the 64 neighbors)
  o0 += __shfl_xor(o0, 16); o0 += __shfl_xor(o0, 32);
  o1 += __shfl_xor(o1, 16); o1 += __shfl_xor(o1, 32);
  o2 += __shfl_xor(o2, 16); o2 += __shfl_xor(o2, 32);
  o3 += __shfl_xor(o3, 16); o3 += __shfl_xor(o3, 32);
  o4 += __shfl_xor(o4, 16); o4 += __shfl_xor(o4, 32);
  o5 += __shfl_xor(o5, 16); o5 += __shfl_xor(o5, 32);
  o6 += __shfl_xor(o6, 16); o6 += __shfl_xor(o6, 32);
  o7 += __shfl_xor(o7, 16); o7 += __shfl_xor(o7, 32);

  // sum_l a_l = 1  =>  out = scale * (self + sum a*(g0[+g1]))
  const float4 sA = *(const float4*)(user_embs + (long)u * E_DIM + j * 8);
  const float4 sB = *(const float4*)(user_embs + (long)u * E_DIM + j * 8 + 4);
  float4 rA, rB;
  rA.x = fmaxf((sA.x + o0) * scale, 0.f);
  rA.y = fmaxf((sA.y + o1) * scale, 0.f);
  rA.z = fmaxf((sA.z + o2) * scale, 0.f);
  rA.w = fmaxf((sA.w + o3) * scale, 0.f);
  rB.x = fmaxf((sB.x + o4) * scale, 0.f);
  rB.y = fmaxf((sB.y + o5) * scale, 0.f);
  rB.z = fmaxf((sB.z + o6) * scale, 0.f);
  rB.w = fmaxf((sB.w + o7) * scale, 0.f);
  if (lane < 16) {  // 16 lanes x 8 dims = full 128-dim row
    float* fp = feats + ((long)k * B + b) * E_DIM + j * 8;
    *(float4*)fp = rA;
    *(float4*)(fp + 4) = rB;
    *(float4*)(&sc[wv][j * 8]) = rA;
    *(float4*)(&sc[wv][j * 8 + 4]) = rB;
  }
  __syncthreads();

  // ---- inter(): hid[j] = b0[j] + sum_e r[e] * W0[e][j] ----
  float hid = b0[lane];
#pragma unroll 4
  for (int e = 0; e < E_DIM; ++e) hid += sc[wv][e] * W0[e * HDIM + lane];
  const float pp = tanhf(hid) * w1[lane];
  const float sum = waveSum(pp);
  if (lane == 0) partials[(long)k * B + b] = sum;
}

// Fallback (proven R4 kernel): fp32 gathers, used only if ws is too small.
__global__ __launch_bounds__(256) void phase1_f32(
    const float* __restrict__ user_embs, const float* __restrict__ item_embs,
    const float* __restrict__ w_uu, const float* __restrict__ w_uiu,
    const float* __restrict__ w_uui, const float* __restrict__ W0,
    const float* __restrict__ b0, const float* __restrict__ w1,
    const int* __restrict__ uid, const int* __restrict__ nbr,
    const int* __restrict__ uiu, const int* __restrict__ uui,
    float* __restrict__ feats, float* __restrict__ partials, int B) {
  const int lane = threadIdx.x & 63;
  const int wv = threadIdx.x >> 6;
  const int w_id = blockIdx.x * 4 + wv;
  const int b = w_id / 3;
  const int k = w_id - 3 * b;
  if (b >= B) return;

  __shared__ float sc[4][E_DIM];
  const int u = uid[b];
  const float self0 = user_embs[u * E_DIM + lane];
  const float self1 = user_embs[u * E_DIM + 64 + lane];
  const float* w = (k == 0) ? w_uu : (k == 1) ? w_uiu : w_uui;
  const float wa0 = w[lane], wa1 = w[64 + lane];
  const float wb0 = w[128 + lane], wb1 = w[192 + lane];
  const float logit_self = waveSum(self0 * wa0 + self1 * wa1);
  const bool is_uu = (k == 0);
  const float scale = is_uu ? 0.5f : (1.0f / 3.0f);
  const float* t0 = (k == 1) ? item_embs : user_embs;
  const float* t1 = (k == 1) ? user_embs : item_embs;
  int i0_l, i1_l;
  if (is_uu) {
    i0_l = nbr[b * L_DIM + lane];
    i1_l = 0;
  } else {
    const int* mp = (k == 1) ? uiu : uui;
    i0_l = mp[(b * 2 + 0) * L_DIM + lane];
    i1_l = mp[(b * 2 + 1) * L_DIM + lane];
  }
  const float mask_l = (i0_l == 0) ? 1.0f : 0.0f;
  float m = -3.0e38f, s = 0.0f, o0 = 0.0f, o1 = 0.0f;
  int i0 = __shfl(i0_l, 0), i1 = __shfl(i1_l, 0);
  float g00 = t0[i0 * E_DIM + lane];
  float g01 = t0[i0 * E_DIM + 64 + lane];
  float g10 = 0.f, g11 = 0.f;
  if (!is_uu) {
    g10 = t1[i1 * E_DIM + lane];
    g11 = t1[i1 * E_DIM + 64 + lane];
  }
  for (int l = 0; l < L_DIM; ++l) {
    const float f0 = (self0 + g00 + g10) * scale;
    const float f1 = (self1 + g01 + g11) * scale;
    if (l < L_DIM - 1) {
      i0 = __shfl(i0_l, l + 1);
      i1 = __shfl(i1_l, l + 1);
      g00 = t0[i0 * E_DIM + lane];
      g01 = t0[i0 * E_DIM + 64 + lane];
      if (!is_uu) {
        g10 = t1[i1 * E_DIM + lane];
        g11 = t1[i1 * E_DIM + 64 + lane];
      }
    }
    float logit = waveSum(f0 * wb0 + f1 * wb1) + logit_self;
    logit = (logit > 0.f) ? logit : 0.01f * logit;
    logit += -100000000.0f * __shfl(mask_l, l);
    const float mn = fmaxf(m, logit);
    const float alpha = __expf(m - mn);
    const float p = __expf(logit - mn);
    s = s * alpha + p;
    o0 = o0 * alpha + p * f0;
    o1 = o1 * alpha + p * f1;
    m = mn;
  }
  const float inv_s = 1.0f / s;
  const float r0 = fmaxf(o0 * inv_s, 0.f);
  const float r1 = fmaxf(o1 * inv_s, 0.f);
  feats[((long)k * B + b) * E_DIM + lane] = r0;
  feats[((long)k * B + b) * E_DIM + 64 + lane] = r1;
  sc[wv][lane] = r0;
  sc[wv][64 + lane] = r1;
  __syncthreads();
  float hid = b0[lane];
#pragma unroll 4
  for (int e = 0; e < E_DIM; ++e) hid += sc[wv][e] * W0[e * HDIM + lane];
  const float p = tanhf(hid) * w1[lane];
  const float sum = waveSum(p);
  if (lane == 0) partials[(long)k * B + b] = sum;
}

__global__ __launch_bounds__(256) void reduce_scores(
    const float* __restrict__ partials, float* __restrict__ weights, int B) {
  __shared__ float red[256];
  const int tid = threadIdx.x;
  float s[3];
#pragma unroll
  for (int k = 0; k < 3; ++k) {
    float acc = 0.f;
    for (int i = tid; i < B; i += 256) acc += partials[(long)k * B + i];
    red[tid] = acc;
    __syncthreads();
    for (int off = 128; off > 0; off >>= 1) {
      if (tid < off) red[tid] += red[tid + off];
      __syncthreads();
    }
    s[k] = red[0];
    __syncthreads();
  }
  if (tid == 0) {
    const float inv_b = 1.0f / (float)B;
    const float s0 = s[0] * inv_b, s1 = s[1] * inv_b, s2 = s[2] * inv_b;
    const float m = fmaxf(s0, fmaxf(s1, s2));
    const float e0 = __expf(s0 - m);
    const float e1 = __expf(s1 - m);
    const float e2 = __expf(s2 - m);
    const float inv = 1.0f / (e0 + e1 + e2);
    weights[0] = e0 * inv;
    weights[1] = e1 * inv;
    weights[2] = e2 * inv;
  }
}

__global__ __launch_bounds__(256) void phase2(
    const float* __restrict__ feats, const float* __restrict__ weights,
    float* __restrict__ out, int B) {
  const int i = blockIdx.x * blockDim.x + threadIdx.x;
  const int n = B * E_DIM;
  if (i >= n) return;
  const float w0 = weights[0], w1 = weights[1], w2 = weights[2];
  const float v = w0 * feats[i] + w1 * feats[n + i] + w2 * feats[2 * n + i];
  out[i] = fmaxf(v, 0.f);
}

extern "C" void kernel_launch(void* const* d_in, const int* in_sizes, int n_in,
                              void* d_out, int out_size, void* d_ws,
                              size_t ws_size, hipStream_t stream) {
  const float* user_embs = (const float*)d_in[0];
  const float* item_embs = (const float*)d_in[1];
  const float* w_uu = (const float*)d_in[2];
  const float* w_uiu = (const float*)d_in[3];
  const float* w_uui = (const float*)d_in[4];
  const float* W0 = (const float*)d_in[5];
  const float* b0 = (const float*)d_in[6];
  const float* w1 = (const float*)d_in[7];
  const int* uid = (const int*)d_in[8];
  const int* nbr = (const int*)d_in[9];
  const int* uiu = (const int*)d_in[10];
  const int* uui = (const int*)d_in[11];
  const int B = in_sizes[8];
  const int nU = in_sizes[0];  // user table elems
  const int nI = in_sizes[1];  // item table elems
  const int nUr = nU / E_DIM;  // user rows
  const int nIr = nI / E_DIM;  // item rows

  float* ws = (float*)d_ws;
  float* partials = ws;            // [3][B]
  float* weights = ws + 3 * B;     // [3] (+pad)
  float* feats = ws + 3 * B + 64;  // [3][B][E]
  const size_t f32_floats = (size_t)3 * B + 64 + (size_t)3 * B * E_DIM;
  unsigned short* user_bf = (unsigned short*)(ws + f32_floats);
  unsigned short* item_bf = user_bf + nU;
  float* projU0 = (float*)(item_bf + nI);
  float* projU1 = projU0 + nUr;
  float* projU2 = projU1 + nUr;
  float* projI1 = projU2 + nUr;
  float* projI2 = projI1 + nIr;
  const size_t need = f32_floats * 4 + ((size_t)nU + nI) * 2 +
                      ((size_t)3 * nUr + 2 * nIr) * 4;

  const int n_waves = 3 * B;
  const int n_blocks = (n_waves + 3) / 4;

  if (ws_size >= need) {
    const int conv_waves = (nUr + nIr + 1) / 2;  // 2 rows per wave
    convert_all<<<(conv_waves + 3) / 4, 256, 0, stream>>>(
        user_embs, item_embs, user_bf, item_bf, w_uu, w_uiu, w_uui, projU0,
        projU1, projU2, projI1, projI2, nUr, nIr);
    phase1_proj<<<n_blocks, 256, 0, stream>>>(
        user_embs, user_bf, item_bf, projU0, projU1, projU2, projI1, projI2,
        w_uu, w_uiu, w_uui, W0, b0, w1, uid, nbr, uiu, uui, feats, partials,
        B);
  } else {
    phase1_f32<<<n_blocks, 256, 0, stream>>>(user_embs, item_embs, w_uu,
                                             w_uiu, w_uui, W0, b0, w1, uid,
                                             nbr, uiu, uui, feats, partials, B);
  }
  reduce_scores<<<1, 256, 0, stream>>>(partials, weights, B);
  const int n = B * E_DIM;
  phase2<<<(n + 255) / 256, 256, 0, stream>>>(feats, weights, (float*)d_out, B);
}

// Round 14
// 213.308 us; speedup vs baseline: 1.0155x; 1.0155x over previous
//
#include <hip/hip_runtime.h>
#include <hip/hip_bf16.h>

#define E_DIM 128
#define L_DIM 64
#define HDIM 64

__device__ __forceinline__ float waveSum(float v) {
#pragma unroll
  for (int o = 32; o > 0; o >>= 1) v += __shfl_xor(v, o);
  return v;
}
__device__ __forceinline__ float waveMax(float v) {
#pragma unroll
  for (int o = 32; o > 0; o >>= 1) v = fmaxf(v, __shfl_xor(v, o));
  return v;
}
__device__ __forceinline__ float halfSum(float v) {  // reduce within 32 lanes
#pragma unroll
  for (int o = 16; o > 0; o >>= 1) v += __shfl_xor(v, o);
  return v;
}

__device__ __forceinline__ unsigned int f2bf(float f) {  // RNE
  unsigned int u = __float_as_uint(f);
  return (u + 0x7fffu + ((u >> 16) & 1u)) >> 16;
}
__device__ __forceinline__ float lo_bf(unsigned int q) {
  return __uint_as_float(q << 16);
}
__device__ __forceinline__ float hi_bf(unsigned int q) {
  return __uint_as_float(q & 0xffff0000u);
}

// Single merged convert pass for BOTH tables. Half-wave h handles global
// row 2*gw+h; user rows first, then item rows. Lane j covers dims
// 4j..4j+3; projection dots reduced over the 32-lane half.
__global__ __launch_bounds__(256) void convert_all(
    const float* __restrict__ user_src, const float* __restrict__ item_src,
    unsigned short* __restrict__ user_bf, unsigned short* __restrict__ item_bf,
    const float* __restrict__ w_uu, const float* __restrict__ w_uiu,
    const float* __restrict__ w_uui, float* __restrict__ pU0,
    float* __restrict__ pU1, float* __restrict__ pU2,
    float* __restrict__ pI1, float* __restrict__ pI2, int nUr, int nIr) {
  const int lane = threadIdx.x & 63;
  const int j = lane & 31;
  const int h = lane >> 5;
  const int gw = blockIdx.x * 4 + (threadIdx.x >> 6);
  const int r_all = gw * 2 + h;
  if (r_all >= nUr + nIr) return;

  const bool is_user = (r_all < nUr);
  const int r = is_user ? r_all : r_all - nUr;
  const float* src = is_user ? user_src : item_src;
  unsigned short* dst = is_user ? user_bf : item_bf;

  const float4 v = *(const float4*)(src + (long)r * E_DIM + j * 4);
  const unsigned int b0p = f2bf(v.x) | (f2bf(v.y) << 16);
  const unsigned int b1p = f2bf(v.z) | (f2bf(v.w) << 16);
  ((uint2*)dst)[(long)r * (E_DIM / 4) + j] = make_uint2(b0p, b1p);
  const float x0 = lo_bf(b0p), x1 = hi_bf(b0p);
  const float x2 = lo_bf(b1p), x3 = hi_bf(b1p);

  const float* wA = is_user ? w_uu : w_uiu;
  const float* wB = is_user ? w_uiu : w_uui;
  const float4 a4 = *(const float4*)(wA + E_DIM + j * 4);
  const float dA = halfSum(x0 * a4.x + x1 * a4.y + x2 * a4.z + x3 * a4.w);
  const float4 b4 = *(const float4*)(wB + E_DIM + j * 4);
  const float dB = halfSum(x0 * b4.x + x1 * b4.y + x2 * b4.z + x3 * b4.w);
  float dC = 0.f;
  if (is_user) {
    const float4 c4 = *(const float4*)(w_uui + E_DIM + j * 4);
    dC = halfSum(x0 * c4.x + x1 * c4.y + x2 * c4.z + x3 * c4.w);
  }
  if (j == 0) {
    if (is_user) {
      pU0[r] = dA;
      pU1[r] = dB;
      pU2[r] = dC;
    } else {
      pI1[r] = dA;
      pI2[r] = dB;
    }
  }
}

// One wave per (b, k). Logits from precomputed row projections (2 softmax
// butterflies total). Weighted sum: QUARTER-WAVE uint4 row loads — each
// 16-lane quarter loads one full 256B bf16 row per instruction, so one
// wave instruction covers 4 rows (R12: this cut phase1 88->69 µs vs 1
// dword/lane; per-instruction TA cost is the limiter, not bytes).
// Rolling depth-1 scalar registers, NO arrays, NO unroll-forced pipeline
// (R8/R10: arrays+unroll -> VGPR 96-108, occ 22%; R13: depth-2 A/B was
// neutral-to-negative — fetch path already saturated at ~2.5 TB/s).
__global__ __launch_bounds__(256) void phase1_proj(
    const float* __restrict__ user_embs,  // fp32 (self rows)
    const unsigned short* __restrict__ user_bf,
    const unsigned short* __restrict__ item_bf,
    const float* __restrict__ projU0, const float* __restrict__ projU1,
    const float* __restrict__ projU2, const float* __restrict__ projI1,
    const float* __restrict__ projI2,
    const float* __restrict__ w_uu, const float* __restrict__ w_uiu,
    const float* __restrict__ w_uui, const float* __restrict__ W0,
    const float* __restrict__ b0, const float* __restrict__ w1,
    const int* __restrict__ uid, const int* __restrict__ nbr,
    const int* __restrict__ uiu, const int* __restrict__ uui,
    float* __restrict__ feats,     // [3][B][E]
    float* __restrict__ partials,  // [3][B]
    int B) {
  const int lane = threadIdx.x & 63;
  const int j = lane & 15;       // dim chunk: dims 8j..8j+7
  const int quarter = lane >> 4; // 0..3: which row of a 4-row group
  const int wv = threadIdx.x >> 6;
  const int w_id = blockIdx.x * 4 + wv;
  const int b = w_id / 3;
  const int k = w_id - 3 * b;
  if (b >= B) return;  // grid exact for B%4==0

  __shared__ float sc[4][E_DIM];

  const int u = uid[b];
  const float2 self2 = *(const float2*)(user_embs + (long)u * E_DIM + lane * 2);

  const float* w = (k == 0) ? w_uu : (k == 1) ? w_uiu : w_uui;
  const float2 wa = *(const float2*)(w + lane * 2);
  const float2 wb = *(const float2*)(w + E_DIM + lane * 2);
  const float S1 = waveSum(self2.x * wa.x + self2.y * wa.y);
  const float S2 = waveSum(self2.x * wb.x + self2.y * wb.y);

  const bool is_uu = (k == 0);
  const float scale = is_uu ? 0.5f : (1.0f / 3.0f);
  // tables: k==0 -> user; k==1 (uiu) -> item,user; k==2 (uui) -> user,item
  const uint4* T0 = (const uint4*)((k == 1) ? item_bf : user_bf);
  const uint4* T1 = (const uint4*)((k == 1) ? user_bf : item_bf);
  const float* p0 = (k == 0) ? projU0 : (k == 1) ? projI1 : projU2;
  const float* p1 = (k == 1) ? projU1 : projI2;  // unused for k==0

  // lane l owns neighbor l's indices (coalesced)
  int i0_l, i1_l;
  if (is_uu) {
    i0_l = nbr[b * L_DIM + lane];
    i1_l = 0;
  } else {
    const int* mp = (k == 1) ? uiu : uui;
    i0_l = mp[(b * 2 + 0) * L_DIM + lane];
    i1_l = mp[(b * 2 + 1) * L_DIM + lane];
  }

  // ---- logits from projections (lane = neighbor, no per-l butterflies) --
  float d = p0[i0_l];
  if (!is_uu) d += p1[i1_l];
  float logit = S1 + scale * (S2 + d);
  logit = (logit > 0.f) ? logit : 0.01f * logit;  // leaky_relu
  if (i0_l == 0) logit += -100000000.0f;          // mask

  const float M = waveMax(logit);
  const float p = __expf(logit - M);
  const float Z = waveSum(p);
  const float a_l = p / Z;  // lane l: neighbor l's attention weight

  // ---- weighted sum: 4 rows/instruction (quarter-wave uint4), depth-1 --
  constexpr int RQ = E_DIM / 8;  // 16 uint4 per bf16 row
  float o0 = 0.f, o1 = 0.f, o2 = 0.f, o3 = 0.f;
  float o4 = 0.f, o5 = 0.f, o6 = 0.f, o7 = 0.f;

  int l4 = quarter;
  float a_cur = __shfl(a_l, l4);
  int i0 = __shfl(i0_l, l4);
  uint4 q0 = T0[(long)i0 * RQ + j];
  uint4 q1 = make_uint4(0, 0, 0, 0);
  if (!is_uu) {
    const int i1 = __shfl(i1_l, l4);
    q1 = T1[(long)i1 * RQ + j];
  }

  for (int it = 0; it < L_DIM / 4; ++it) {
    const float a = a_cur;
    const uint4 qa = q0;
    const uint4 qb = q1;
    if (it < L_DIM / 4 - 1) {  // prefetch next 4-row group
      l4 = 4 * (it + 1) + quarter;
      a_cur = __shfl(a_l, l4);
      i0 = __shfl(i0_l, l4);
      q0 = T0[(long)i0 * RQ + j];
      if (!is_uu) {
        const int i1 = __shfl(i1_l, l4);
        q1 = T1[(long)i1 * RQ + j];
      }
    }
    float h0 = lo_bf(qa.x), h1 = hi_bf(qa.x);
    float h2 = lo_bf(qa.y), h3 = hi_bf(qa.y);
    float h4 = lo_bf(qa.z), h5 = hi_bf(qa.z);
    float h6 = lo_bf(qa.w), h7 = hi_bf(qa.w);
    if (!is_uu) {
      h0 += lo_bf(qb.x); h1 += hi_bf(qb.x);
      h2 += lo_bf(qb.y); h3 += hi_bf(qb.y);
      h4 += lo_bf(qb.z); h5 += hi_bf(qb.z);
      h6 += lo_bf(qb.w); h7 += hi_bf(qb.w);
    }
    o0 += a * h0; o1 += a * h1; o2 += a * h2; o3 += a * h3;
    o4 += a * h4; o5 += a * h5; o6 += a * h6; o7 += a * h7;
  }
  // combine the 4 quarters (each summed 16 of the 64 neighbors)
  o0 += __shfl_xor(o0, 16); o0 += __shfl_xor(o0, 32);
  o1 += __shfl_xor(o1, 16); o1 += __shfl_xor(o1, 32);
  o2 += __shfl_xor(o2, 16); o2 += __shfl_xor(o2, 32);
  o3 += __shfl_xor(o3, 16); o3 += __shfl_xor(o3, 32);
  o4 += __shfl_xor(o4, 16); o4 += __shfl_xor(o4, 32);
  o5 += __shfl_xor(o5, 16); o5 += __shfl_xor(o5, 32);
  o6 += __shfl_xor(o6, 16); o6 += __shfl_xor(o6, 32);
  o7 += __shfl_xor(o7, 16); o7 += __shfl_xor(o7, 32);

  // sum_l a_l = 1  =>  out = scale * (self + sum a*(g0[+g1]))
  const float4 sA = *(const float4*)(user_embs + (long)u * E_DIM + j * 8);
  const float4 sB = *(const float4*)(user_embs + (long)u * E_DIM + j * 8 + 4);
  float4 rA, rB;
  rA.x = fmaxf((sA.x + o0) * scale, 0.f);
  rA.y = fmaxf((sA.y + o1) * scale, 0.f);
  rA.z = fmaxf((sA.z + o2) * scale, 0.f);
  rA.w = fmaxf((sA.w + o3) * scale, 0.f);
  rB.x = fmaxf((sB.x + o4) * scale, 0.f);
  rB.y = fmaxf((sB.y + o5) * scale, 0.f);
  rB.z = fmaxf((sB.z + o6) * scale, 0.f);
  rB.w = fmaxf((sB.w + o7) * scale, 0.f);
  if (lane < 16) {  // 16 lanes x 8 dims = full 128-dim row
    float* fp = feats + ((long)k * B + b) * E_DIM + j * 8;
    *(float4*)fp = rA;
    *(float4*)(fp + 4) = rB;
    *(float4*)(&sc[wv][j * 8]) = rA;
    *(float4*)(&sc[wv][j * 8 + 4]) = rB;
  }
  __syncthreads();

  // ---- inter(): hid[j] = b0[j] + sum_e r[e] * W0[e][j] ----
  float hid = b0[lane];
#pragma unroll 4
  for (int e = 0; e < E_DIM; ++e) hid += sc[wv][e] * W0[e * HDIM + lane];
  const float pp = tanhf(hid) * w1[lane];
  const float sum = waveSum(pp);
  if (lane == 0) partials[(long)k * B + b] = sum;
}

// Fallback (proven R4 kernel): fp32 gathers, used only if ws is too small.
__global__ __launch_bounds__(256) void phase1_f32(
    const float* __restrict__ user_embs, const float* __restrict__ item_embs,
    const float* __restrict__ w_uu, const float* __restrict__ w_uiu,
    const float* __restrict__ w_uui, const float* __restrict__ W0,
    const float* __restrict__ b0, const float* __restrict__ w1,
    const int* __restrict__ uid, const int* __restrict__ nbr,
    const int* __restrict__ uiu, const int* __restrict__ uui,
    float* __restrict__ feats, float* __restrict__ partials, int B) {
  const int lane = threadIdx.x & 63;
  const int wv = threadIdx.x >> 6;
  const int w_id = blockIdx.x * 4 + wv;
  const int b = w_id / 3;
  const int k = w_id - 3 * b;
  if (b >= B) return;

  __shared__ float sc[4][E_DIM];
  const int u = uid[b];
  const float self0 = user_embs[u * E_DIM + lane];
  const float self1 = user_embs[u * E_DIM + 64 + lane];
  const float* w = (k == 0) ? w_uu : (k == 1) ? w_uiu : w_uui;
  const float wa0 = w[lane], wa1 = w[64 + lane];
  const float wb0 = w[128 + lane], wb1 = w[192 + lane];
  const float logit_self = waveSum(self0 * wa0 + self1 * wa1);
  const bool is_uu = (k == 0);
  const float scale = is_uu ? 0.5f : (1.0f / 3.0f);
  const float* t0 = (k == 1) ? item_embs : user_embs;
  const float* t1 = (k == 1) ? user_embs : item_embs;
  int i0_l, i1_l;
  if (is_uu) {
    i0_l = nbr[b * L_DIM + lane];
    i1_l = 0;
  } else {
    const int* mp = (k == 1) ? uiu : uui;
    i0_l = mp[(b * 2 + 0) * L_DIM + lane];
    i1_l = mp[(b * 2 + 1) * L_DIM + lane];
  }
  const float mask_l = (i0_l == 0) ? 1.0f : 0.0f;
  float m = -3.0e38f, s = 0.0f, o0 = 0.0f, o1 = 0.0f;
  int i0 = __shfl(i0_l, 0), i1 = __shfl(i1_l, 0);
  float g00 = t0[i0 * E_DIM + lane];
  float g01 = t0[i0 * E_DIM + 64 + lane];
  float g10 = 0.f, g11 = 0.f;
  if (!is_uu) {
    g10 = t1[i1 * E_DIM + lane];
    g11 = t1[i1 * E_DIM + 64 + lane];
  }
  for (int l = 0; l < L_DIM; ++l) {
    const float f0 = (self0 + g00 + g10) * scale;
    const float f1 = (self1 + g01 + g11) * scale;
    if (l < L_DIM - 1) {
      i0 = __shfl(i0_l, l + 1);
      i1 = __shfl(i1_l, l + 1);
      g00 = t0[i0 * E_DIM + lane];
      g01 = t0[i0 * E_DIM + 64 + lane];
      if (!is_uu) {
        g10 = t1[i1 * E_DIM + lane];
        g11 = t1[i1 * E_DIM + 64 + lane];
      }
    }
    float logit = waveSum(f0 * wb0 + f1 * wb1) + logit_self;
    logit = (logit > 0.f) ? logit : 0.01f * logit;
    logit += -100000000.0f * __shfl(mask_l, l);
    const float mn = fmaxf(m, logit);
    const float alpha = __expf(m - mn);
    const float p = __expf(logit - mn);
    s = s * alpha + p;
    o0 = o0 * alpha + p * f0;
    o1 = o1 * alpha + p * f1;
    m = mn;
  }
  const float inv_s = 1.0f / s;
  const float r0 = fmaxf(o0 * inv_s, 0.f);
  const float r1 = fmaxf(o1 * inv_s, 0.f);
  feats[((long)k * B + b) * E_DIM + lane] = r0;
  feats[((long)k * B + b) * E_DIM + 64 + lane] = r1;
  sc[wv][lane] = r0;
  sc[wv][64 + lane] = r1;
  __syncthreads();
  float hid = b0[lane];
#pragma unroll 4
  for (int e = 0; e < E_DIM; ++e) hid += sc[wv][e] * W0[e * HDIM + lane];
  const float p = tanhf(hid) * w1[lane];
  const float sum = waveSum(p);
  if (lane == 0) partials[(long)k * B + b] = sum;
}

__global__ __launch_bounds__(256) void reduce_scores(
    const float* __restrict__ partials, float* __restrict__ weights, int B) {
  __shared__ float red[256];
  const int tid = threadIdx.x;
  float s[3];
#pragma unroll
  for (int k = 0; k < 3; ++k) {
    float acc = 0.f;
    for (int i = tid; i < B; i += 256) acc += partials[(long)k * B + i];
    red[tid] = acc;
    __syncthreads();
    for (int off = 128; off > 0; off >>= 1) {
      if (tid < off) red[tid] += red[tid + off];
      __syncthreads();
    }
    s[k] = red[0];
    __syncthreads();
  }
  if (tid == 0) {
    const float inv_b = 1.0f / (float)B;
    const float s0 = s[0] * inv_b, s1 = s[1] * inv_b, s2 = s[2] * inv_b;
    const float m = fmaxf(s0, fmaxf(s1, s2));
    const float e0 = __expf(s0 - m);
    const float e1 = __expf(s1 - m);
    const float e2 = __expf(s2 - m);
    const float inv = 1.0f / (e0 + e1 + e2);
    weights[0] = e0 * inv;
    weights[1] = e1 * inv;
    weights[2] = e2 * inv;
  }
}

__global__ __launch_bounds__(256) void phase2(
    const float* __restrict__ feats, const float* __restrict__ weights,
    float* __restrict__ out, int B) {
  const int i = blockIdx.x * blockDim.x + threadIdx.x;
  const int n = B * E_DIM;
  if (i >= n) return;
  const float w0 = weights[0], w1 = weights[1], w2 = weights[2];
  const float v = w0 * feats[i] + w1 * feats[n + i] + w2 * feats[2 * n + i];
  out[i] = fmaxf(v, 0.f);
}

extern "C" void kernel_launch(void* const* d_in, const int* in_sizes, int n_in,
                              void* d_out, int out_size, void* d_ws,
                              size_t ws_size, hipStream_t stream) {
  const float* user_embs = (const float*)d_in[0];
  const float* item_embs = (const float*)d_in[1];
  const float* w_uu = (const float*)d_in[2];
  const float* w_uiu = (const float*)d_in[3];
  const float* w_uui = (const float*)d_in[4];
  const float* W0 = (const float*)d_in[5];
  const float* b0 = (const float*)d_in[6];
  const float* w1 = (const float*)d_in[7];
  const int* uid = (const int*)d_in[8];
  const int* nbr = (const int*)d_in[9];
  const int* uiu = (const int*)d_in[10];
  const int* uui = (const int*)d_in[11];
  const int B = in_sizes[8];
  const int nU = in_sizes[0];  // user table elems
  const int nI = in_sizes[1];  // item table elems
  const int nUr = nU / E_DIM;  // user rows
  const int nIr = nI / E_DIM;  // item rows

  float* ws = (float*)d_ws;
  float* partials = ws;            // [3][B]
  float* weights = ws + 3 * B;     // [3] (+pad)
  float* feats = ws + 3 * B + 64;  // [3][B][E]
  const size_t f32_floats = (size_t)3 * B + 64 + (size_t)3 * B * E_DIM;
  unsigned short* user_bf = (unsigned short*)(ws + f32_floats);
  unsigned short* item_bf = user_bf + nU;
  float* projU0 = (float*)(item_bf + nI);
  float* projU1 = projU0 + nUr;
  float* projU2 = projU1 + nUr;
  float* projI1 = projU2 + nUr;
  float* projI2 = projI1 + nIr;
  const size_t need = f32_floats * 4 + ((size_t)nU + nI) * 2 +
                      ((size_t)3 * nUr + 2 * nIr) * 4;

  const int n_waves = 3 * B;
  const int n_blocks = (n_waves + 3) / 4;

  if (ws_size >= need) {
    const int conv_waves = (nUr + nIr + 1) / 2;  // 2 rows per wave
    convert_all<<<(conv_waves + 3) / 4, 256, 0, stream>>>(
        user_embs, item_embs, user_bf, item_bf, w_uu, w_uiu, w_uui, projU0,
        projU1, projU2, projI1, projI2, nUr, nIr);
    phase1_proj<<<n_blocks, 256, 0, stream>>>(
        user_embs, user_bf, item_bf, projU0, projU1, projU2, projI1, projI2,
        w_uu, w_uiu, w_uui, W0, b0, w1, uid, nbr, uiu, uui, feats, partials,
        B);
  } else {
    phase1_f32<<<n_blocks, 256, 0, stream>>>(user_embs, item_embs, w_uu,
                                             w_uiu, w_uui, W0, b0, w1, uid,
                                             nbr, uiu, uui, feats, partials, B);
  }
  reduce_scores<<<1, 256, 0, stream>>>(partials, weights, B);
  const int n = B * E_DIM;
  phase2<<<(n + 255) / 256, 256, 0, stream>>>(feats, weights, (float*)d_out, B);
}